// Round 4
// baseline (209.020 us; speedup 1.0000x reference)
//
#include <hip/hip_runtime.h>
#include <hip/hip_bf16.h>
#include <hip/hip_fp16.h>

#define LOG2PI_F 1.8378770664093453f
#define LOG2E_F  1.44269504f

typedef float f32x4 __attribute__((ext_vector_type(4)));
typedef short s16x8 __attribute__((ext_vector_type(8)));
typedef _Float16 f16x8 __attribute__((ext_vector_type(8)));
typedef _Float16 f16x2 __attribute__((ext_vector_type(2)));
typedef unsigned short u16;

// ---- workspace layout (float offsets into d_ws) ----
#define OFF_PREC   0        // f32 [8][16][16]
#define OFF_LOGDET 2048     // f32 [8]
#define OFF_LTR    2064     // f32 [8][8]   log(softmax(T)+1e-8) * log2e
#define OFF_LINI   2128     // f32 [8]      log softmax(init)    * log2e
#define OFF_CHAIN  2144     // int [8][16]
#define OFF_CNT    2272     // int [8]      bucket counts
#define OFF_PERM   2304     // int [8][512] bucketed batch ids
#define OFF_ELL    8192     // f32 [512][8][128]  (scaled by log2e)  [b][s][f]
#define OFF_WT     532480   // u16(bf16) [8][128][16][16]  Wt[s][l][d][c]
#define OFF_WF     663552   // u16(f16)  [8][128][16][16]  Wf[s][l][d][c]

__device__ inline u16 f2bf(float x) {
  union { float f; unsigned u; } v; v.f = x;
  unsigned r = v.u + 0x7fffu + ((v.u >> 16) & 1u);  // RNE
  return (u16)(r >> 16);
}
__device__ inline int swz(int a) { return a ^ (((a >> 9) & 7) << 4); }

// ---------------------------------------------------------------------------
// kernel 1: blocks 0..1023 build Wt(bf16)+Wf(f16); block 1024 does prep
// ---------------------------------------------------------------------------
__global__ __launch_bounds__(256) void prep_wt_kernel(const float* __restrict__ tmat,
                                                      const float* __restrict__ initd,
                                                      const float* __restrict__ cc,
                                                      const float* __restrict__ W,
                                                      float* __restrict__ ws) {
  __shared__ float Ls[8][16][16];
  __shared__ float Cv[8][16][16];
  __shared__ float tmp[256];
  int t = threadIdx.x;

  if (blockIdx.x < 1024) {                       // ---- Wt/Wf build ----
    u16* Wt = (u16*)(ws + OFF_WT);
    u16* Wf = (u16*)(ws + OFF_WF);
    int sl = blockIdx.x;
    tmp[t] = W[sl * 256 + t];
    __syncthreads();
    int d = t >> 4, c = t & 15;
    float x = tmp[c * 16 + d];                   // out[d][c] = in[c][d]
    Wt[sl * 256 + t] = f2bf(x);
    Wf[sl * 256 + t] = __half_as_ushort(__float2half(x));
    return;
  }

  // ---- prep ----
  float* prec   = ws + OFF_PREC;
  float* logdet = ws + OFF_LOGDET;
  float* ltr    = ws + OFF_LTR;
  float* lini   = ws + OFF_LINI;
  int*   chain  = (int*)(ws + OFF_CHAIN);

  if (t < 128) {                                 // chol = tril(cc,-1)+diag(exp(diag))
    int s = t >> 4, i = t & 15;
    const float* c0 = cc + s * 256 + i * 16;
    for (int j = 0; j < 16; ++j) {
      float v = c0[j];
      Ls[s][i][j] = (i > j) ? v : (i == j ? expf(v) : 0.f);
    }
  }
  __syncthreads();
  if (t < 128) {                                 // covar = chol@chol^T + 1e-6 I
    int s = t >> 4, i = t & 15;
    for (int j = 0; j <= i; ++j) {
      float sum = (i == j) ? 1e-6f : 0.f;
      for (int k = 0; k <= j; ++k) sum += Ls[s][i][k] * Ls[s][j][k];
      Cv[s][i][j] = sum; Cv[s][j][i] = sum;
    }
  }
  __syncthreads();
  if (t < 8) {                                   // cholesky of covar -> Ls
    int s = t;
    for (int j = 0; j < 16; ++j) {
      float dv = Cv[s][j][j];
      for (int k = 0; k < j; ++k) dv -= Ls[s][j][k] * Ls[s][j][k];
      dv = sqrtf(dv);
      Ls[s][j][j] = dv;
      for (int i = j + 1; i < 16; ++i) {
        float v = Cv[s][i][j];
        for (int k = 0; k < j; ++k) v -= Ls[s][i][k] * Ls[s][j][k];
        Ls[s][i][j] = v / dv;
      }
    }
    float ld = 0.f;
    for (int j = 0; j < 16; ++j) ld += logf(Ls[s][j][j]);
    logdet[s] = 2.f * ld;
  } else if (t == 8) {
    float m = -1e30f;
    for (int i = 0; i < 8; ++i) m = fmaxf(m, initd[i]);
    float sum = 0.f;
    for (int i = 0; i < 8; ++i) sum += expf(initd[i] - m);
    float ls = logf(sum);
    for (int i = 0; i < 8; ++i) lini[i] = (initd[i] - m - ls) * LOG2E_F;
  } else if (t == 9) {
    int nxt[8];
    for (int i = 0; i < 8; ++i) {
      float best = -1e30f; int bi = 0;
      for (int j = 0; j < 8; ++j) {
        float v = tmat[i * 8 + j];
        if (v > best) { best = v; bi = j; }
      }
      nxt[i] = bi;
    }
    for (int s0 = 0; s0 < 8; ++s0) {
      int c = s0;
      for (int k = 0; k < 16; ++k) { c = nxt[c]; chain[s0 * 16 + k] = c; }
    }
  } else if (t == 10) {
    int* cnt = (int*)(ws + OFF_CNT);
    for (int i = 0; i < 8; ++i) cnt[i] = 0;      // re-zero every call (graph-safe)
  } else if (t >= 16 && t < 24) {
    int i = t - 16;
    float m = -1e30f;
    for (int j = 0; j < 8; ++j) m = fmaxf(m, tmat[i * 8 + j]);
    float sum = 0.f;
    for (int j = 0; j < 8; ++j) sum += expf(tmat[i * 8 + j] - m);
    for (int j = 0; j < 8; ++j)
      ltr[i * 8 + j] = logf(expf(tmat[i * 8 + j] - m) / sum + 1e-8f) * LOG2E_F;
  }
  __syncthreads();
  if (t < 128) {                                 // prec = inv(covar)
    int s = t >> 4, col = t & 15;
    float y[16], x[16];
#pragma unroll
    for (int i = 0; i < 16; ++i) {
      float v = (i == col) ? 1.f : 0.f;
#pragma unroll
      for (int k = 0; k < 16; ++k) if (k < i) v -= Ls[s][i][k] * y[k];
      y[i] = v / Ls[s][i][i];
    }
#pragma unroll
    for (int i = 15; i >= 0; --i) {
      float v = y[i];
#pragma unroll
      for (int k = 0; k < 16; ++k) if (k > i) v -= Ls[s][k][i] * x[k];
      x[i] = v / Ls[s][i][i];
    }
#pragma unroll
    for (int i = 0; i < 16; ++i) prec[s * 256 + i * 16 + col] = x[i];
  }
}

// ---------------------------------------------------------------------------
// emis: block = (state-pair, batch-group of 4); MFMA bf16; swizzled A-LDS
// ---------------------------------------------------------------------------
__global__ __launch_bounds__(256, 2) void emis_kernel(const float* __restrict__ emis,
                                                      const float* __restrict__ means,
                                                      float* __restrict__ ws) {
  const float* prec   = ws + OFF_PREC;
  const float* logdet = ws + OFF_LOGDET;
  const u16* Wt = (const u16*)(ws + OFF_WT);
  float* ell = ws + OFF_ELL;

  int sp = blockIdx.x & 3;
  int bg = blockIdx.x >> 2;
  int s0 = sp * 2;
  int bb0 = bg * 4;
  int tid = threadIdx.x;

  __shared__ u16  padh[4][256][16];   // 32 KB, XOR-swizzled 16B slots
  __shared__ float diffL[4][128][20]; // 40 KB, 80B row stride

  char* pbase = (char*)&padh[0][0][0];
  const s16x8 zero8 = {0, 0, 0, 0, 0, 0, 0, 0};

  for (int i = tid; i < 1024; i += 256)
    *(s16x8*)(pbase + (i >> 8) * 8192 + (i & 255) * 16) = zero8;
  for (int i = tid; i < 1024; i += 256) {
    int g = i >> 8, erow = (i >> 1) & 127, h = i & 1;
    const f32x4* src = (const f32x4*)(emis + (size_t)(bb0 + g) * 2048 + erow * 16 + h * 8);
    f32x4 v0 = src[0], v1 = src[1];
    s16x8 pk;
#pragma unroll
    for (int c = 0; c < 4; ++c) { pk[c] = (short)f2bf(v0[c]); pk[c + 4] = (short)f2bf(v1[c]); }
    int row = 128 + erow;
    int off = ((row << 5) + (h << 4)) ^ (((row >> 2) & 3) << 4);
    *(s16x8*)(pbase + g * 8192 + off) = pk;
  }
  __syncthreads();

  int wave = tid >> 6, lane = tid & 63;
  int rc = lane & 15;
  int h  = (lane >> 4) & 1;
  int dl = lane >> 5;
  int hh = h << 4;
  int m1 = wave, m2 = 7 - wave;
  int k1 = 56 - 8 * m1, k2 = 56 - 8 * m2;
  int r01 = m1 * 16 + rc + dl, r02 = m2 * 16 + rc + dl;

  const u16* Bb0 = Wt + ((size_t)((s0 * 128 + dl) * 16 + rc) * 16) + h * 8 + (size_t)k2 * 512;
  const u16* Bb1 = Bb0 + 32768;

  f32x4 acc[2][4][2] = {};

  s16x8 w0 = *(const s16x8*)Bb0, w1 = *(const s16x8*)Bb1;
  int kk = k2;
  for (; kk < k1; ++kk) {
    s16x8 n0, n1;
    if (kk < 63) { n0 = *(const s16x8*)(Bb0 + 512); n1 = *(const s16x8*)(Bb1 + 512); }
    Bb0 += 512; Bb1 += 512;
    int row2 = r02 + 2 * kk;
    const char* pa = pbase + (((row2 << 5) + hh) ^ (((row2 >> 2) & 3) << 4));
#pragma unroll
    for (int g = 0; g < 4; ++g) {
      s16x8 a = *(const s16x8*)(pa + g * 8192);
      acc[0][g][0] = __builtin_amdgcn_mfma_f32_16x16x32_bf16(a, w0, acc[0][g][0], 0, 0, 0);
      acc[1][g][0] = __builtin_amdgcn_mfma_f32_16x16x32_bf16(a, w1, acc[1][g][0], 0, 0, 0);
    }
    w0 = n0; w1 = n1;
  }
  for (; kk < 64; ++kk) {
    s16x8 n0, n1;
    if (kk < 63) { n0 = *(const s16x8*)(Bb0 + 512); n1 = *(const s16x8*)(Bb1 + 512); }
    Bb0 += 512; Bb1 += 512;
    int row2 = r02 + 2 * kk, row1 = r01 + 2 * kk;
    const char* pa2 = pbase + (((row2 << 5) + hh) ^ (((row2 >> 2) & 3) << 4));
    const char* pa1 = pbase + (((row1 << 5) + hh) ^ (((row1 >> 2) & 3) << 4));
#pragma unroll
    for (int g = 0; g < 4; ++g) {
      s16x8 a2 = *(const s16x8*)(pa2 + g * 8192);
      acc[0][g][0] = __builtin_amdgcn_mfma_f32_16x16x32_bf16(a2, w0, acc[0][g][0], 0, 0, 0);
      acc[1][g][0] = __builtin_amdgcn_mfma_f32_16x16x32_bf16(a2, w1, acc[1][g][0], 0, 0, 0);
      s16x8 a1 = *(const s16x8*)(pa1 + g * 8192);
      acc[0][g][1] = __builtin_amdgcn_mfma_f32_16x16x32_bf16(a1, w0, acc[0][g][1], 0, 0, 0);
      acc[1][g][1] = __builtin_amdgcn_mfma_f32_16x16x32_bf16(a1, w1, acc[1][g][1], 0, 0, 0);
    }
    w0 = n0; w1 = n1;
  }

  int hi = (lane >> 4) & 3;
#pragma unroll
  for (int s = 0; s < 2; ++s) {
    float mn = means[(s0 + s) * 16 + rc];
#pragma unroll
    for (int tt = 0; tt < 2; ++tt) {
      int m = tt ? m1 : m2;
#pragma unroll
      for (int g = 0; g < 4; ++g) {
#pragma unroll
        for (int r = 0; r < 4; ++r) {
          int f = m * 16 + hi * 4 + r;
          diffL[g][f][rc] =
            emis[(size_t)(bb0 + g) * 2048 + f * 16 + rc] - acc[s][g][tt][r] - mn;
        }
      }
    }
    __syncthreads();
    const float* P = prec + (s0 + s) * 256;
    float c2 = -0.72134752f * (logdet[s0 + s] + 16.f * LOG2PI_F);
#pragma unroll
    for (int it = 0; it < 2; ++it) {
      int task = tid + it * 256;
      int g = task >> 7, f = task & 127;
      float dv[16];
#pragma unroll
      for (int c = 0; c < 4; ++c)
        *(f32x4*)&dv[c * 4] = *(const f32x4*)&diffL[g][f][c * 4];
      float qq = 0.f;
#pragma unroll
      for (int c = 0; c < 16; ++c) {
        float tsum = 0.5f * P[c * 16 + c] * dv[c];
#pragma unroll
        for (int d = 0; d < 16; ++d)
          if (d > c) tsum = fmaf(P[c * 16 + d], dv[d], tsum);
        qq = fmaf(dv[c], tsum, qq);
      }
      // coalesced: consecutive tid -> consecutive f
      ell[((size_t)(bb0 + g) * 8 + s0 + s) * 128 + f] = fmaf(-2.f * 0.72134752f, qq, c2);
    }
    if (s == 0) __syncthreads();
  }
}

// ---------------------------------------------------------------------------
// forward scan + argmax + bucketing; register-prefetched ell chunks
// ---------------------------------------------------------------------------
__global__ __launch_bounds__(64) void fwd_kernel(float* __restrict__ ws) {
  const float* ell  = ws + OFF_ELL;
  const float* ltr  = ws + OFF_LTR;
  const float* lini = ws + OFF_LINI;
  int* cnt  = (int*)(ws + OFF_CNT);
  int* perm = (int*)(ws + OFF_PERM);
  int gidx = blockIdx.x * 64 + threadIdx.x;
  int b = gidx >> 3, s = gidx & 7;
  const f32x4* src = (const f32x4*)(ell + (size_t)gidx * 128);
  float ltc[8];
#pragma unroll
  for (int i = 0; i < 8; ++i) ltc[i] = ltr[i * 8 + s];

  float la;
  auto step = [&](float e) {
    float v[8]; float m = -1e30f;
#pragma unroll
    for (int i = 0; i < 8; ++i) { v[i] = __shfl(la, i, 8) + ltc[i]; m = fmaxf(m, v[i]); }
    float sum = 0.f;
#pragma unroll
    for (int i = 0; i < 8; ++i) sum += exp2f(v[i] - m);
    la = m + log2f(sum) + e;
  };

  float eA[16], eB[16];
#pragma unroll
  for (int c = 0; c < 4; ++c) *(f32x4*)&eA[c * 4] = src[c];
#pragma unroll
  for (int c = 0; c < 4; ++c) *(f32x4*)&eB[c * 4] = src[4 + c];
  la = lini[s] + eA[0];
#pragma unroll
  for (int j = 1; j < 16; ++j) step(eA[j]);
#pragma unroll 1
  for (int ch = 1; ch < 8; ++ch) {
    float eC[16];
#pragma unroll
    for (int j = 0; j < 16; ++j) eC[j] = eB[j];
    if (ch < 7) {
#pragma unroll
      for (int c = 0; c < 4; ++c) *(f32x4*)&eB[c * 4] = src[(ch + 1) * 4 + c];
    }
#pragma unroll
    for (int j = 0; j < 16; ++j) step(eC[j]);
  }

  float best = -1e30f; int bi = 0;
#pragma unroll
  for (int i = 0; i < 8; ++i) {
    float o = __shfl(la, i, 8);
    if (o > best) { best = o; bi = i; }   // first-max rule
  }
  if (s == 0) {
    int pos = atomicAdd(&cnt[bi], 1);     // order varies; output order-independent
    perm[bi * 512 + pos] = b;
  }
}

// ---------------------------------------------------------------------------
// AR prediction: bucketed (8 same-chain batches/block, wave=batch, no barriers)
// f16 weights via v_dot2_f32_f16; swizzled f16 lag buffer in LDS
// ---------------------------------------------------------------------------
__global__ __launch_bounds__(512) void pred_kernel(const float* __restrict__ emis,
                                                   const float* __restrict__ means,
                                                   float* __restrict__ ws,
                                                   float* __restrict__ out) {
  const int* chain = (const int*)(ws + OFF_CHAIN);
  const int* cnt   = (const int*)(ws + OFF_CNT);
  const int* perm  = (const int*)(ws + OFF_PERM);
  const u16* Wf = (const u16*)(ws + OFF_WF);
  __shared__ u16 buf16[8][2048];        // [wave][128 rows x 16 c] f16, swizzled

  int bucket = blockIdx.x >> 6, slot = blockIdx.x & 63;
  int nb = cnt[bucket];
  int wave = threadIdx.x >> 6, lane = threadIdx.x & 63;
  int bidx = slot * 8 + wave;
  if (bidx >= nb) return;               // no __syncthreads below -> safe
  int b = perm[bucket * 512 + bidx];
  char* mybuf = (char*)&buf16[wave][0];

  // stage emissions rows 2*lane, 2*lane+1 as f16
#pragma unroll
  for (int r2 = 0; r2 < 2; ++r2) {
    int row = lane * 2 + r2;
    const f32x4* srcp = (const f32x4*)(emis + (size_t)b * 2048 + row * 16);
    f32x4 v0 = srcp[0], v1 = srcp[1], v2 = srcp[2], v3 = srcp[3];
    f16x8 p0, p1;
#pragma unroll
    for (int j = 0; j < 4; ++j) {
      p0[j] = (_Float16)v0[j]; p0[4 + j] = (_Float16)v1[j];
      p1[j] = (_Float16)v2[j]; p1[4 + j] = (_Float16)v3[j];
    }
    *(f16x8*)(mybuf + swz(row * 32))      = p0;
    *(f16x8*)(mybuf + swz(row * 32 + 16)) = p1;
  }

  int g = lane >> 3, dh = lane & 7;     // lane = g*8 + dh
  int start = 0;
  for (int k = 0; k < 16; ++k) {
    int st = chain[bucket * 16 + k];    // block-uniform -> scalar
    const u16* Wb = Wf + (size_t)st * 32768;
    float a0 = 0.f, a1 = 0.f;
#pragma unroll
    for (int j = 0; j < 16; ++j) {
      int l = g * 16 + j;
      int row = (start + l) & 127;
      f16x8 e0 = *(const f16x8*)(mybuf + swz(row * 32));        // c 0..7 (bcast x8)
      f16x8 e1 = *(const f16x8*)(mybuf + swz(row * 32 + 16));   // c 8..15
      const u16* wp0 = Wb + l * 256 + dh * 16;                  // d = dh
      const u16* wp1 = wp0 + 128;                               // d = dh+8
      f16x8 wA0 = *(const f16x8*)wp0;
      f16x8 wA1 = *(const f16x8*)(wp0 + 8);
      f16x8 wB0 = *(const f16x8*)wp1;
      f16x8 wB1 = *(const f16x8*)(wp1 + 8);
#pragma unroll
      for (int q = 0; q < 4; ++q) {
        f16x2 pe0 = {e0[2 * q], e0[2 * q + 1]};
        f16x2 pe1 = {e1[2 * q], e1[2 * q + 1]};
        f16x2 cA0 = {wA0[2 * q], wA0[2 * q + 1]};
        f16x2 cA1 = {wA1[2 * q], wA1[2 * q + 1]};
        f16x2 cB0 = {wB0[2 * q], wB0[2 * q + 1]};
        f16x2 cB1 = {wB1[2 * q], wB1[2 * q + 1]};
        a0 = __builtin_amdgcn_fdot2(pe0, cA0, a0, false);
        a1 = __builtin_amdgcn_fdot2(pe0, cB0, a1, false);
        a0 = __builtin_amdgcn_fdot2(pe1, cA1, a0, false);
        a1 = __builtin_amdgcn_fdot2(pe1, cB1, a1, false);
      }
    }
    // reduce over g (lane bits 3..5) -> all lanes hold full sums
    a0 += __shfl_xor(a0, 8);  a1 += __shfl_xor(a1, 8);
    a0 += __shfl_xor(a0, 16); a1 += __shfl_xor(a1, 16);
    a0 += __shfl_xor(a0, 32); a1 += __shfl_xor(a1, 32);
    int rn = start;
    if (lane < 8) {
      float o0 = a0 + means[st * 16 + dh];
      float o1 = a1 + means[st * 16 + dh + 8];
      out[b * 256 + k * 16 + dh]     = o0;
      out[b * 256 + k * 16 + dh + 8] = o1;
      *(u16*)(mybuf + swz(rn * 32 + dh * 2))      = __half_as_ushort(__float2half(o0));
      *(u16*)(mybuf + swz(rn * 32 + 16 + dh * 2)) = __half_as_ushort(__float2half(o1));
    }
    start = (start + 1) & 127;
  }
}

extern "C" void kernel_launch(void* const* d_in, const int* in_sizes, int n_in,
                              void* d_out, int out_size, void* d_ws, size_t ws_size,
                              hipStream_t stream) {
  const float* emis  = (const float*)d_in[0];
  const float* tmat  = (const float*)d_in[1];
  const float* initd = (const float*)d_in[2];
  const float* means = (const float*)d_in[3];
  const float* cc    = (const float*)d_in[4];
  const float* W     = (const float*)d_in[5];
  float* ws  = (float*)d_ws;
  float* out = (float*)d_out;

  hipLaunchKernelGGL(prep_wt_kernel, dim3(1025), dim3(256), 0, stream, tmat, initd, cc, W, ws);
  hipLaunchKernelGGL(emis_kernel, dim3(512), dim3(256), 0, stream, emis, means, ws);
  hipLaunchKernelGGL(fwd_kernel, dim3(64), dim3(64), 0, stream, ws);
  hipLaunchKernelGGL(pred_kernel, dim3(512), dim3(512), 0, stream, emis, means, ws, out);
}

// Round 5
// 111.221 us; speedup vs baseline: 1.8793x; 1.8793x over previous
//
#include <hip/hip_runtime.h>
#include <hip/hip_bf16.h>

#define LOG2PI_F 1.8378770664093453f
#define LOG2E_F  1.44269504f

typedef float f32x4 __attribute__((ext_vector_type(4)));
typedef short s16x8 __attribute__((ext_vector_type(8)));
typedef unsigned short u16;

// ---- workspace layout (float offsets into d_ws) ----
#define OFF_PREC   0        // f32 [8][16][16]
#define OFF_LOGDET 2048     // f32 [8]
#define OFF_LTR    2064     // f32 [8][8]   log(softmax(T)+1e-8) * log2e
#define OFF_LINI   2128     // f32 [8]      log softmax(init)    * log2e
#define OFF_CHAIN  2144     // int [8][16]
#define OFF_CNT    2272     // int [8]      bucket counts
#define OFF_PERM   2304     // int [8][512] bucketed batch ids
#define OFF_ELL    8192     // f32 [512][8][128]  (scaled by log2e)  [b][s][f]
#define OFF_WT     532480   // u16(bf16) [8][128][16][16]  Wt[s][l][d][c]

__device__ inline u16 f2bf(float x) {
  union { float f; unsigned u; } v; v.f = x;
  unsigned r = v.u + 0x7fffu + ((v.u >> 16) & 1u);  // RNE
  return (u16)(r >> 16);
}

// ---------------------------------------------------------------------------
// kernel 1: blocks 0..1023 build Wt(bf16); block 1024 does prep
// ---------------------------------------------------------------------------
__global__ __launch_bounds__(256) void prep_wt_kernel(const float* __restrict__ tmat,
                                                      const float* __restrict__ initd,
                                                      const float* __restrict__ cc,
                                                      const float* __restrict__ W,
                                                      float* __restrict__ ws) {
  __shared__ float Ls[8][16][16];
  __shared__ float Cv[8][16][16];
  __shared__ float tmp[256];
  int t = threadIdx.x;

  if (blockIdx.x < 1024) {                       // ---- Wt build ----
    u16* Wt = (u16*)(ws + OFF_WT);
    int sl = blockIdx.x;
    tmp[t] = W[sl * 256 + t];
    __syncthreads();
    int d = t >> 4, c = t & 15;
    Wt[sl * 256 + t] = f2bf(tmp[c * 16 + d]);    // out[d][c] = in[c][d]
    return;
  }

  // ---- prep ----
  float* prec   = ws + OFF_PREC;
  float* logdet = ws + OFF_LOGDET;
  float* ltr    = ws + OFF_LTR;
  float* lini   = ws + OFF_LINI;
  int*   chain  = (int*)(ws + OFF_CHAIN);

  if (t < 128) {                                 // chol = tril(cc,-1)+diag(exp(diag))
    int s = t >> 4, i = t & 15;
    const float* c0 = cc + s * 256 + i * 16;
    for (int j = 0; j < 16; ++j) {
      float v = c0[j];
      Ls[s][i][j] = (i > j) ? v : (i == j ? expf(v) : 0.f);
    }
  }
  __syncthreads();
  if (t < 128) {                                 // covar = chol@chol^T + 1e-6 I
    int s = t >> 4, i = t & 15;
    for (int j = 0; j <= i; ++j) {
      float sum = (i == j) ? 1e-6f : 0.f;
      for (int k = 0; k <= j; ++k) sum += Ls[s][i][k] * Ls[s][j][k];
      Cv[s][i][j] = sum; Cv[s][j][i] = sum;
    }
  }
  __syncthreads();
  if (t < 8) {                                   // cholesky of covar -> Ls
    int s = t;
    for (int j = 0; j < 16; ++j) {
      float dv = Cv[s][j][j];
      for (int k = 0; k < j; ++k) dv -= Ls[s][j][k] * Ls[s][j][k];
      dv = sqrtf(dv);
      Ls[s][j][j] = dv;
      for (int i = j + 1; i < 16; ++i) {
        float v = Cv[s][i][j];
        for (int k = 0; k < j; ++k) v -= Ls[s][i][k] * Ls[s][j][k];
        Ls[s][i][j] = v / dv;
      }
    }
    float ld = 0.f;
    for (int j = 0; j < 16; ++j) ld += logf(Ls[s][j][j]);
    logdet[s] = 2.f * ld;
  } else if (t == 8) {
    float m = -1e30f;
    for (int i = 0; i < 8; ++i) m = fmaxf(m, initd[i]);
    float sum = 0.f;
    for (int i = 0; i < 8; ++i) sum += expf(initd[i] - m);
    float ls = logf(sum);
    for (int i = 0; i < 8; ++i) lini[i] = (initd[i] - m - ls) * LOG2E_F;
  } else if (t == 9) {
    int nxt[8];
    for (int i = 0; i < 8; ++i) {
      float best = -1e30f; int bi = 0;
      for (int j = 0; j < 8; ++j) {
        float v = tmat[i * 8 + j];
        if (v > best) { best = v; bi = j; }
      }
      nxt[i] = bi;
    }
    for (int s0 = 0; s0 < 8; ++s0) {
      int c = s0;
      for (int k = 0; k < 16; ++k) { c = nxt[c]; chain[s0 * 16 + k] = c; }
    }
  } else if (t == 10) {
    int* cnt = (int*)(ws + OFF_CNT);
    for (int i = 0; i < 8; ++i) cnt[i] = 0;      // re-zero every call (graph-safe)
  } else if (t >= 16 && t < 24) {
    int i = t - 16;
    float m = -1e30f;
    for (int j = 0; j < 8; ++j) m = fmaxf(m, tmat[i * 8 + j]);
    float sum = 0.f;
    for (int j = 0; j < 8; ++j) sum += expf(tmat[i * 8 + j] - m);
    for (int j = 0; j < 8; ++j)
      ltr[i * 8 + j] = logf(expf(tmat[i * 8 + j] - m) / sum + 1e-8f) * LOG2E_F;
  }
  __syncthreads();
  if (t < 128) {                                 // prec = inv(covar)
    int s = t >> 4, col = t & 15;
    float y[16], x[16];
#pragma unroll
    for (int i = 0; i < 16; ++i) {
      float v = (i == col) ? 1.f : 0.f;
#pragma unroll
      for (int k = 0; k < 16; ++k) if (k < i) v -= Ls[s][i][k] * y[k];
      y[i] = v / Ls[s][i][i];
    }
#pragma unroll
    for (int i = 15; i >= 0; --i) {
      float v = y[i];
#pragma unroll
      for (int k = 0; k < 16; ++k) if (k > i) v -= Ls[s][k][i] * x[k];
      x[i] = v / Ls[s][i][i];
    }
#pragma unroll
    for (int i = 0; i < 16; ++i) prec[s * 256 + i * 16 + col] = x[i];
  }
}

// ---------------------------------------------------------------------------
// emis: block = (state-pair, batch-group of 4); MFMA bf16; swizzled A-LDS
// ---------------------------------------------------------------------------
__global__ __launch_bounds__(256, 2) void emis_kernel(const float* __restrict__ emis,
                                                      const float* __restrict__ means,
                                                      float* __restrict__ ws) {
  const float* prec   = ws + OFF_PREC;
  const float* logdet = ws + OFF_LOGDET;
  const u16* Wt = (const u16*)(ws + OFF_WT);
  float* ell = ws + OFF_ELL;

  int sp = blockIdx.x & 3;
  int bg = blockIdx.x >> 2;
  int s0 = sp * 2;
  int bb0 = bg * 4;
  int tid = threadIdx.x;

  __shared__ u16  padh[4][256][16];   // 32 KB, XOR-swizzled 16B slots
  __shared__ float diffL[4][128][20]; // 40 KB, 80B row stride

  char* pbase = (char*)&padh[0][0][0];
  const s16x8 zero8 = {0, 0, 0, 0, 0, 0, 0, 0};

  for (int i = tid; i < 1024; i += 256)
    *(s16x8*)(pbase + (i >> 8) * 8192 + (i & 255) * 16) = zero8;
  for (int i = tid; i < 1024; i += 256) {
    int g = i >> 8, erow = (i >> 1) & 127, h = i & 1;
    const f32x4* src = (const f32x4*)(emis + (size_t)(bb0 + g) * 2048 + erow * 16 + h * 8);
    f32x4 v0 = src[0], v1 = src[1];
    s16x8 pk;
#pragma unroll
    for (int c = 0; c < 4; ++c) { pk[c] = (short)f2bf(v0[c]); pk[c + 4] = (short)f2bf(v1[c]); }
    int row = 128 + erow;
    int off = ((row << 5) + (h << 4)) ^ (((row >> 2) & 3) << 4);
    *(s16x8*)(pbase + g * 8192 + off) = pk;
  }
  __syncthreads();

  int wave = tid >> 6, lane = tid & 63;
  int rc = lane & 15;
  int h  = (lane >> 4) & 1;
  int dl = lane >> 5;
  int hh = h << 4;
  int m1 = wave, m2 = 7 - wave;
  int k1 = 56 - 8 * m1, k2 = 56 - 8 * m2;
  int r01 = m1 * 16 + rc + dl, r02 = m2 * 16 + rc + dl;

  const u16* Bb0 = Wt + ((size_t)((s0 * 128 + dl) * 16 + rc) * 16) + h * 8 + (size_t)k2 * 512;
  const u16* Bb1 = Bb0 + 32768;

  f32x4 acc[2][4][2] = {};

  s16x8 w0 = *(const s16x8*)Bb0, w1 = *(const s16x8*)Bb1;
  int kk = k2;
  for (; kk < k1; ++kk) {
    s16x8 n0, n1;
    if (kk < 63) { n0 = *(const s16x8*)(Bb0 + 512); n1 = *(const s16x8*)(Bb1 + 512); }
    Bb0 += 512; Bb1 += 512;
    int row2 = r02 + 2 * kk;
    const char* pa = pbase + (((row2 << 5) + hh) ^ (((row2 >> 2) & 3) << 4));
#pragma unroll
    for (int g = 0; g < 4; ++g) {
      s16x8 a = *(const s16x8*)(pa + g * 8192);
      acc[0][g][0] = __builtin_amdgcn_mfma_f32_16x16x32_bf16(a, w0, acc[0][g][0], 0, 0, 0);
      acc[1][g][0] = __builtin_amdgcn_mfma_f32_16x16x32_bf16(a, w1, acc[1][g][0], 0, 0, 0);
    }
    w0 = n0; w1 = n1;
  }
  for (; kk < 64; ++kk) {
    s16x8 n0, n1;
    if (kk < 63) { n0 = *(const s16x8*)(Bb0 + 512); n1 = *(const s16x8*)(Bb1 + 512); }
    Bb0 += 512; Bb1 += 512;
    int row2 = r02 + 2 * kk, row1 = r01 + 2 * kk;
    const char* pa2 = pbase + (((row2 << 5) + hh) ^ (((row2 >> 2) & 3) << 4));
    const char* pa1 = pbase + (((row1 << 5) + hh) ^ (((row1 >> 2) & 3) << 4));
#pragma unroll
    for (int g = 0; g < 4; ++g) {
      s16x8 a2 = *(const s16x8*)(pa2 + g * 8192);
      acc[0][g][0] = __builtin_amdgcn_mfma_f32_16x16x32_bf16(a2, w0, acc[0][g][0], 0, 0, 0);
      acc[1][g][0] = __builtin_amdgcn_mfma_f32_16x16x32_bf16(a2, w1, acc[1][g][0], 0, 0, 0);
      s16x8 a1 = *(const s16x8*)(pa1 + g * 8192);
      acc[0][g][1] = __builtin_amdgcn_mfma_f32_16x16x32_bf16(a1, w0, acc[0][g][1], 0, 0, 0);
      acc[1][g][1] = __builtin_amdgcn_mfma_f32_16x16x32_bf16(a1, w1, acc[1][g][1], 0, 0, 0);
    }
    w0 = n0; w1 = n1;
  }

  int hi = (lane >> 4) & 3;
#pragma unroll
  for (int s = 0; s < 2; ++s) {
    float mn = means[(s0 + s) * 16 + rc];
#pragma unroll
    for (int tt = 0; tt < 2; ++tt) {
      int m = tt ? m1 : m2;
#pragma unroll
      for (int g = 0; g < 4; ++g) {
#pragma unroll
        for (int r = 0; r < 4; ++r) {
          int f = m * 16 + hi * 4 + r;
          diffL[g][f][rc] =
            emis[(size_t)(bb0 + g) * 2048 + f * 16 + rc] - acc[s][g][tt][r] - mn;
        }
      }
    }
    __syncthreads();
    const float* P = prec + (s0 + s) * 256;
    float c2 = -0.72134752f * (logdet[s0 + s] + 16.f * LOG2PI_F);
#pragma unroll
    for (int it = 0; it < 2; ++it) {
      int task = tid + it * 256;
      int g = task >> 7, f = task & 127;
      float dv[16];
#pragma unroll
      for (int c = 0; c < 4; ++c)
        *(f32x4*)&dv[c * 4] = *(const f32x4*)&diffL[g][f][c * 4];
      float qq = 0.f;
#pragma unroll
      for (int c = 0; c < 16; ++c) {
        float tsum = 0.5f * P[c * 16 + c] * dv[c];
#pragma unroll
        for (int d = 0; d < 16; ++d)
          if (d > c) tsum = fmaf(P[c * 16 + d], dv[d], tsum);
        qq = fmaf(dv[c], tsum, qq);
      }
      ell[((size_t)(bb0 + g) * 8 + s0 + s) * 128 + f] = fmaf(-2.f * 0.72134752f, qq, c2);
    }
    if (s == 0) __syncthreads();
  }
}

// ---------------------------------------------------------------------------
// forward scan + argmax + bucketing; register-prefetched ell chunks
// ---------------------------------------------------------------------------
__global__ __launch_bounds__(64) void fwd_kernel(float* __restrict__ ws) {
  const float* ell  = ws + OFF_ELL;
  const float* ltr  = ws + OFF_LTR;
  const float* lini = ws + OFF_LINI;
  int* cnt  = (int*)(ws + OFF_CNT);
  int* perm = (int*)(ws + OFF_PERM);
  int gidx = blockIdx.x * 64 + threadIdx.x;
  int b = gidx >> 3, s = gidx & 7;
  const f32x4* src = (const f32x4*)(ell + (size_t)gidx * 128);
  float ltc[8];
#pragma unroll
  for (int i = 0; i < 8; ++i) ltc[i] = ltr[i * 8 + s];

  float la;
  auto step = [&](float e) {
    float v[8]; float m = -1e30f;
#pragma unroll
    for (int i = 0; i < 8; ++i) { v[i] = __shfl(la, i, 8) + ltc[i]; m = fmaxf(m, v[i]); }
    float sum = 0.f;
#pragma unroll
    for (int i = 0; i < 8; ++i) sum += exp2f(v[i] - m);
    la = m + log2f(sum) + e;
  };

  float eA[16], eB[16];
#pragma unroll
  for (int c = 0; c < 4; ++c) *(f32x4*)&eA[c * 4] = src[c];
#pragma unroll
  for (int c = 0; c < 4; ++c) *(f32x4*)&eB[c * 4] = src[4 + c];
  la = lini[s] + eA[0];
#pragma unroll
  for (int j = 1; j < 16; ++j) step(eA[j]);
#pragma unroll 1
  for (int ch = 1; ch < 8; ++ch) {
    float eC[16];
#pragma unroll
    for (int j = 0; j < 16; ++j) eC[j] = eB[j];
    if (ch < 7) {
#pragma unroll
      for (int c = 0; c < 4; ++c) *(f32x4*)&eB[c * 4] = src[(ch + 1) * 4 + c];
    }
#pragma unroll
    for (int j = 0; j < 16; ++j) step(eC[j]);
  }

  float best = -1e30f; int bi = 0;
#pragma unroll
  for (int i = 0; i < 8; ++i) {
    float o = __shfl(la, i, 8);
    if (o > best) { best = o; bi = i; }   // first-max rule
  }
  if (s == 0) {
    int pos = atomicAdd(&cnt[bi], 1);     // order varies; output order-independent
    perm[bi * 512 + pos] = b;
  }
}

// ---------------------------------------------------------------------------
// AR prediction via MFMA: block = 16 same-bucket batches, 4 waves.
// Per step: C[16 batch][16 d] = A(buf 16x2048 bf16) x B(Wt[st]) in 64 MFMAs
// (wave w owns kk=w*16..w*16+15), LDS partial-reduce by wave 0, feedback row
// written as bf16. Bank-conflict-free via batch-XOR swizzle.
// ---------------------------------------------------------------------------
__global__ __launch_bounds__(256, 2) void pred_kernel(const float* __restrict__ emis,
                                                      const float* __restrict__ means,
                                                      float* __restrict__ ws,
                                                      float* __restrict__ out) {
  const int* chain = (const int*)(ws + OFF_CHAIN);
  const int* cnt   = (const int*)(ws + OFF_CNT);
  const int* perm  = (const int*)(ws + OFF_PERM);
  const u16* Wt = (const u16*)(ws + OFF_WT);

  __shared__ u16 buf[16][128][16];     // 64 KB bf16 lag buffers, batch-XOR swizzled
  __shared__ float part[4][64][4];     // 4 KB wave partials
  __shared__ int bid[16];

  int bucket = blockIdx.x >> 5, slot = blockIdx.x & 31;
  int nb = cnt[bucket];
  int base = slot * 16;
  if (base >= nb) return;              // block-uniform -> safe before barriers
  int tid = threadIdx.x;
  char* pb = (char*)&buf[0][0][0];

  if (tid < 16) {
    int idx = base + tid;
    bid[tid] = perm[bucket * 512 + (idx < nb ? idx : base)];  // pad = dup first
  }
  __syncthreads();

  // stage emissions for 16 batches as bf16 (rows 0..127), swizzled
  for (int i = tid; i < 2048; i += 256) {
    int b = i >> 7, row = i & 127;
    const f32x4* sp = (const f32x4*)(emis + (size_t)bid[b] * 2048 + row * 16);
    f32x4 v0 = sp[0], v1 = sp[1], v2 = sp[2], v3 = sp[3];
    s16x8 p0, p1;
#pragma unroll
    for (int j = 0; j < 4; ++j) {
      p0[j] = (short)f2bf(v0[j]); p0[4 + j] = (short)f2bf(v1[j]);
      p1[j] = (short)f2bf(v2[j]); p1[4 + j] = (short)f2bf(v3[j]);
    }
    int xo = (b & 7) << 4;
    int bse = b * 4096 + row * 32;
    *(s16x8*)(pb + (bse ^ xo)) = p0;
    *(s16x8*)(pb + ((bse + 16) ^ xo)) = p1;
  }
  __syncthreads();

  int wave = tid >> 6, lane = tid & 63;
  int rc = lane & 15;                  // A: batch | B: d | C: d
  int q  = lane >> 4;
  int h  = q & 1;                      // c-half
  int dl = q >> 1;                     // lag within 32-k step
  int axor = (rc & 7) << 4;
  const int* mychain = chain + bucket * 16;

  int start = 0;
  for (int k = 0; k < 16; ++k) {
    int st = mychain[k];
    const u16* Bb = Wt + ((size_t)((st * 128 + dl) * 16 + rc) * 16) + h * 8;
    f32x4 accA = {0.f, 0.f, 0.f, 0.f}, accB = {0.f, 0.f, 0.f, 0.f};
#pragma unroll
    for (int t2 = 0; t2 < 8; ++t2) {
      int kkA = wave * 16 + t2 * 2, kkB = kkA + 1;
      s16x8 wA = *(const s16x8*)(Bb + (size_t)kkA * 512);
      s16x8 wB = *(const s16x8*)(Bb + (size_t)kkB * 512);
      int rowA = (start + kkA * 2 + dl) & 127;
      int rowB = (start + kkB * 2 + dl) & 127;
      s16x8 aA = *(const s16x8*)(pb + ((rc * 4096 + rowA * 32 + h * 16) ^ axor));
      s16x8 aB = *(const s16x8*)(pb + ((rc * 4096 + rowB * 32 + h * 16) ^ axor));
      accA = __builtin_amdgcn_mfma_f32_16x16x32_bf16(aA, wA, accA, 0, 0, 0);
      accB = __builtin_amdgcn_mfma_f32_16x16x32_bf16(aB, wB, accB, 0, 0, 0);
    }
    f32x4 acc = accA + accB;
    *(f32x4*)&part[wave][lane][0] = acc;
    __syncthreads();
    if (wave == 0) {
      f32x4 c0s = *(f32x4*)&part[0][lane][0];
      f32x4 c1s = *(f32x4*)&part[1][lane][0];
      f32x4 c2s = *(f32x4*)&part[2][lane][0];
      f32x4 c3s = *(f32x4*)&part[3][lane][0];
      f32x4 cs = (c0s + c1s) + (c2s + c3s);
      float mn = means[st * 16 + rc];            // rc = d here
#pragma unroll
      for (int r = 0; r < 4; ++r) {
        int b = q * 4 + r;                       // C row = batch
        float v = cs[r] + mn;
        if (base + b < nb)
          out[(size_t)bid[b] * 256 + k * 16 + rc] = v;
        *(u16*)(pb + ((b * 4096 + start * 32 + rc * 2) ^ ((b & 7) << 4))) = f2bf(v);
      }
    }
    __syncthreads();
    start = (start + 1) & 127;
  }
}

extern "C" void kernel_launch(void* const* d_in, const int* in_sizes, int n_in,
                              void* d_out, int out_size, void* d_ws, size_t ws_size,
                              hipStream_t stream) {
  const float* emis  = (const float*)d_in[0];
  const float* tmat  = (const float*)d_in[1];
  const float* initd = (const float*)d_in[2];
  const float* means = (const float*)d_in[3];
  const float* cc    = (const float*)d_in[4];
  const float* W     = (const float*)d_in[5];
  float* ws  = (float*)d_ws;
  float* out = (float*)d_out;

  hipLaunchKernelGGL(prep_wt_kernel, dim3(1025), dim3(256), 0, stream, tmat, initd, cc, W, ws);
  hipLaunchKernelGGL(emis_kernel, dim3(512), dim3(256), 0, stream, emis, means, ws);
  hipLaunchKernelGGL(fwd_kernel, dim3(64), dim3(64), 0, stream, ws);
  hipLaunchKernelGGL(pred_kernel, dim3(256), dim3(256), 0, stream, emis, means, ws, out);
}